// Round 3
// baseline (201.940 us; speedup 1.0000x reference)
//
#include <hip/hip_runtime.h>

// GlobalAttentionPooling: tensor_square_0e -> selu -> @W -> segment softmax -> weighted segment sum
// N nodes, 80 f32 ft (32 scalar + 16 x 3-vec), NG=1024 graphs (sorted batch_index), F=664.
//
// Identities (validated rounds 1-2, absmax 3.9e-3):
//   selu const term cancels in softmax; pre-scale s by sqrt(log2e), v by sqrt(log2e/sqrt3)
//   so pair products are f*log2e -> exp2 directly. out_g = (sum nf*ex)/z_g.
//
// Round-3 structure:
//   pass1: 1 node/thread, f2 packing along j-pairs of the triangle (invalid slot -> w=0),
//          2-stage LDS bounce (40KB) for coalesced global loads, 1172 blocks, 4 blocks/CU.
//   pass2: fused z+weighted sum (each c4 column owns a full copy of z), 640 thr/block,
//          2x unrolled dual accumulators.

typedef float f2 __attribute__((ext_vector_type(2)));

#define C0 32
#define C1 16
#define NODE_F 80
#define NG_CONST 1024

#define SELU_SCALE 1.0507009873554804934193349852946
#define SELU_ALPHA 1.6732632423543772848170429916717
#define LOG2E      1.4426950408889634073599246810019

#define CS_SCALE 1.2011224087864498f    // sqrt(log2e)
#define CV_SCALE 0.91271231102878545f   // sqrt(log2e/sqrt(3))

// triu flat indices (compile-time after unroll)
#define KS(i, j) ((i) * C0 - ((i) * ((i) -1)) / 2 + ((j) - (i)))
#define KV(i, j) (528 + (i) * C1 - ((i) * ((i) -1)) / 2 + ((j) - (i)))

__global__ __launch_bounds__(256, 4) void pass1_logits(
    const float* __restrict__ nf, const float* __restrict__ W,
    float* __restrict__ ex_out, int N)
{
    __shared__ float4 buf[128 * 20];       // 40 KB bounce buffer (128 rows)
    const int tid = threadIdx.x;
    const int base_row = blockIdx.x * 256;
    const int total4 = N * 20;             // float4 count of nf
    const float4* g4 = (const float4*)nf;

    float4 row4[20];                       // this thread's row (80 floats)
    const int half = tid >> 7;             // 0: rows 0-127, 1: rows 128-255
    const int r    = tid & 127;

    // ---- stage 0: rows base..base+127, coalesced ----
    #pragma unroll
    for (int it = 0; it < 10; ++it) {
        int g = base_row * 20 + it * 256 + tid;
        buf[it * 256 + tid] = g4[g < total4 ? g : 0];   // clamp: tail rows get junk, never stored
    }
    __syncthreads();
    if (half == 0) {
        const float4* src = &buf[r * 20];
        #pragma unroll
        for (int q = 0; q < 20; ++q) row4[q] = src[q];
    }
    __syncthreads();                       // stage-0 reads done before overwrite
    // ---- stage 1: rows base+128..base+255 ----
    #pragma unroll
    for (int it = 0; it < 10; ++it) {
        int g = (base_row + 128) * 20 + it * 256 + tid;
        buf[it * 256 + tid] = g4[g < total4 ? g : 0];
    }
    __syncthreads();
    if (half == 1) {
        const float4* src = &buf[r * 20];
        #pragma unroll
        for (int q = 0; q < 20; ++q) row4[q] = src[q];
    }

    const float* row = (const float*)row4;

    f2 accA[2], accB[2];
    accA[0] = 0.f; accA[1] = 0.f; accB[0] = 0.f; accB[1] = 0.f;

    // ---------- phase S: 32 scalar channels, 528 triu pairs as j-pair f2 ----------
    {
        f2 s2[C0 / 2];
        #pragma unroll
        for (int q = 0; q < C0 / 2; ++q)
            s2[q] = f2{row[2 * q], row[2 * q + 1]} * CS_SCALE;

        #pragma unroll
        for (int i = 0; i < C0; ++i) {
            const float si = (i & 1) ? s2[i >> 1].y : s2[i >> 1].x;
            const f2 si2 = f2{si, si};
            #pragma unroll
            for (int q = i / 2; q < C0 / 2; ++q) {
                f2 f = si2 * s2[q];                         // {f(i,2q), f(i,2q+1)} * log2e
                f2 p = __builtin_elementwise_max(f, (f2)0.f);
                f2 m = __builtin_elementwise_min(f, (f2)0.f);
                f2 e; e.x = __builtin_amdgcn_exp2f(m.x);
                      e.y = __builtin_amdgcn_exp2f(m.y);
                f2 w;
                w.x = (2 * q >= i) ? W[KS(i, 2 * q)] : 0.0f;  // pad slot (i odd) -> 0
                w.y = W[KS(i, 2 * q + 1)];
                accA[q & 1] = __builtin_elementwise_fma(w, p, accA[q & 1]);
                accB[q & 1] = __builtin_elementwise_fma(w, e, accB[q & 1]);
            }
        }
    }

    // ---------- phase V: 16 3-vec channels, 136 triu dot pairs as j-pair f2 ----------
    {
        f2 vp[C1 / 2][3];                  // vp[q][c] = {v[2q][c], v[2q+1][c]} * CV
        #pragma unroll
        for (int q = 0; q < C1 / 2; ++q) {
            #pragma unroll
            for (int c = 0; c < 3; ++c)
                vp[q][c] = f2{row[C0 + 6 * q + c], row[C0 + 6 * q + 3 + c]} * CV_SCALE;
        }
        #pragma unroll
        for (int i = 0; i < C1; ++i) {
            const int iq = i >> 1;
            float vi0 = (i & 1) ? vp[iq][0].y : vp[iq][0].x;
            float vi1 = (i & 1) ? vp[iq][1].y : vp[iq][1].x;
            float vi2 = (i & 1) ? vp[iq][2].y : vp[iq][2].x;
            #pragma unroll
            for (int q = i / 2; q < C1 / 2; ++q) {
                f2 f = f2{vi0, vi0} * vp[q][0];
                f = __builtin_elementwise_fma(f2{vi1, vi1}, vp[q][1], f);
                f = __builtin_elementwise_fma(f2{vi2, vi2}, vp[q][2], f);
                f2 p = __builtin_elementwise_max(f, (f2)0.f);
                f2 m = __builtin_elementwise_min(f, (f2)0.f);
                f2 e; e.x = __builtin_amdgcn_exp2f(m.x);
                      e.y = __builtin_amdgcn_exp2f(m.y);
                f2 w;
                w.x = (2 * q >= i) ? W[KV(i, 2 * q)] : 0.0f;
                w.y = W[KV(i, 2 * q + 1)];
                accA[q & 1] = __builtin_elementwise_fma(w, p, accA[q & 1]);
                accB[q & 1] = __builtin_elementwise_fma(w, e, accB[q & 1]);
            }
        }
    }

    const float A1 = accA[0].x + accA[0].y + accA[1].x + accA[1].y;
    const float A2 = accB[0].x + accB[0].y + accB[1].x + accB[1].y;
    const float l2 = fmaf((float)SELU_SCALE, A1,
                          (float)(SELU_SCALE * SELU_ALPHA * LOG2E) * A2);
    const int n = base_row + tid;
    if (n < N) ex_out[n] = __builtin_amdgcn_exp2f(l2);
}

__global__ __launch_bounds__(256) void seg_bounds_kernel(
    const int* __restrict__ bi, int* __restrict__ bounds, int N)
{
    const int g = blockIdx.x * blockDim.x + threadIdx.x;
    if (g > NG_CONST) return;
    int lo = 0, hi = N;
    while (lo < hi) {
        int mid = (lo + hi) >> 1;
        if (bi[mid] < g) lo = mid + 1; else hi = mid;
    }
    bounds[g] = lo;
}

#define P2T 640   // 32 nodes x 20 float4-channel-groups

__global__ __launch_bounds__(P2T) void pass2_pool(
    const float* __restrict__ nf, const float* __restrict__ ex,
    const int* __restrict__ bounds, float* __restrict__ out)
{
    __shared__ float4 red4[P2T];
    __shared__ float  zred[P2T];
    const int g = blockIdx.x;
    const int tid = threadIdx.x;
    const int start = bounds[g];
    const int end   = bounds[g + 1];

    const int no = tid / 20;      // 0..31
    const int c4 = tid % 20;
    const float4* nf4 = (const float4*)nf;

    // fused: weighted feature sum + z (each c4 column accumulates a full copy of z)
    float4 a0 = make_float4(0.f, 0.f, 0.f, 0.f), a1 = a0;
    float  z0 = 0.f, z1 = 0.f;
    int n = start + no;
    for (; n + 32 < end; n += 64) {
        float  w0 = ex[n];
        float4 v0 = nf4[(size_t)n * 20 + c4];
        float  w1 = ex[n + 32];
        float4 v1 = nf4[(size_t)(n + 32) * 20 + c4];
        a0.x = fmaf(v0.x, w0, a0.x); a0.y = fmaf(v0.y, w0, a0.y);
        a0.z = fmaf(v0.z, w0, a0.z); a0.w = fmaf(v0.w, w0, a0.w);
        z0 += w0;
        a1.x = fmaf(v1.x, w1, a1.x); a1.y = fmaf(v1.y, w1, a1.y);
        a1.z = fmaf(v1.z, w1, a1.z); a1.w = fmaf(v1.w, w1, a1.w);
        z1 += w1;
    }
    if (n < end) {
        float  w0 = ex[n];
        float4 v0 = nf4[(size_t)n * 20 + c4];
        a0.x = fmaf(v0.x, w0, a0.x); a0.y = fmaf(v0.y, w0, a0.y);
        a0.z = fmaf(v0.z, w0, a0.z); a0.w = fmaf(v0.w, w0, a0.w);
        z0 += w0;
    }
    a0.x += a1.x; a0.y += a1.y; a0.z += a1.z; a0.w += a1.w;
    z0 += z1;

    red4[tid] = a0;
    zred[tid] = z0;
    __syncthreads();
    #pragma unroll
    for (int s = 16; s > 0; s >>= 1) {
        if (no < s) {
            float4 o = red4[tid + s * 20];
            red4[tid].x += o.x; red4[tid].y += o.y;
            red4[tid].z += o.z; red4[tid].w += o.w;
            zred[tid] += zred[tid + s * 20];
        }
        __syncthreads();
    }
    if (tid < 20) {
        float z = zred[tid];
        float inv_z = (z > 0.0f) ? (1.0f / z) : 0.0f;
        float4 r = red4[tid];
        r.x *= inv_z; r.y *= inv_z; r.z *= inv_z; r.w *= inv_z;
        ((float4*)(out + (size_t)g * NODE_F))[tid] = r;
    }
}

extern "C" void kernel_launch(void* const* d_in, const int* in_sizes, int n_in,
                              void* d_out, int out_size, void* d_ws, size_t ws_size,
                              hipStream_t stream) {
    const float* nf = (const float*)d_in[0];   // (N, 80) f32
    const int*   bi = (const int*)d_in[1];     // (N,) i32 sorted
    // d_in[2] = num_graphs (static 1024)
    const float* W  = (const float*)d_in[3];   // (664,) f32
    float* out = (float*)d_out;

    const int N = in_sizes[0] / NODE_F;
    float* ex     = (float*)d_ws;              // N floats
    int*   bounds = (int*)d_ws + N;            // NG+1 ints

    hipLaunchKernelGGL(seg_bounds_kernel, dim3((NG_CONST + 256) / 256), dim3(256),
                       0, stream, bi, bounds, N);
    hipLaunchKernelGGL(pass1_logits, dim3((N + 255) / 256), dim3(256),
                       0, stream, nf, W, ex, N);
    hipLaunchKernelGGL(pass2_pool, dim3(NG_CONST), dim3(P2T),
                       0, stream, nf, ex, bounds, out);
}